// Round 4
// baseline (54.134 us; speedup 1.0000x reference)
//
#include <hip/hip_runtime.h>

// V-trace advantage estimation, T x T output.
// out[t][j] = g_t(j) - values[j]
// g_t(j) = sum_{k>=0} delta_{t+k} * ratio_j^k * prod_{u=t}^{t+k-1} q_u
// with q_u = (1-gamma)*(1-done_u) <= 0.01, ratio_j <= 1.
// Truncate at K=4: dropped term <= |delta|*(0.01)^4 ~ 1e-7.
//
// Geometry (round 4): 2048 blocks (8/CU, max occupancy = 32 waves/CU),
// each wave writes 2 KB CONTIGUOUS per row (2 x 1 KB f32x4 stores),
// isolating burst-length vs round 2 (1 KB/wave) at IDENTICAL occupancy.

typedef float f32x4 __attribute__((ext_vector_type(4)));

#define GAMMA_F 0.99f

__global__ __launch_bounds__(256) void vtrace_adv_kernel(
    const float* __restrict__ rewards,
    const float* __restrict__ values,
    const float* __restrict__ next_values,
    const float* __restrict__ dones,
    const float* __restrict__ worker_lp,
    const float* __restrict__ learner_lp,
    float* __restrict__ out,
    int T)
{
    constexpr int ROWS   = 16;   // rows (t) per block -> grid_y = T/16 = 512
    constexpr int K      = 4;    // Horner terms
    constexpr int EXT    = ROWS + K;
    constexpr int CHUNKS = 2;    // f32x4 chunks per thread, 1 KB apart in wave
    // block covers 2048 columns; wave w -> 512 cols contiguous (2 KB)

    __shared__ float s_delta[EXT];
    __shared__ float s_q[EXT];
    __shared__ f32x4 s_w[ROWS];   // per-row Horner coefficients

    const int tid  = threadIdx.x;
    const int wave = tid >> 6;
    const int lane = tid & 63;
    const int t0   = blockIdx.y * ROWS;
    // wave-contiguous column base: chunk c covers [col0 + c*256, +4)
    const int col0 = blockIdx.x * 2048 + wave * 512 + lane * 4;

    // ---- cooperative: delta[t], q[t] for window [t0, t0+EXT) ----
    if (tid < EXT) {
        int s = t0 + tid;
        float d = 0.f, q = 0.f;
        if (s < T) {
            float ratio = fminf(1.f, __expf(learner_lp[s] - worker_lp[s]));
            float nd = 1.f - dones[s];
            d = ratio * (rewards[s] + nd * GAMMA_F * next_values[s]);
            q = (1.f - GAMMA_F) * nd;
        }
        s_delta[tid] = d;
        s_q[tid] = q;
    }
    __syncthreads();

    // ---- per-row coefficients w[r][k] = delta[t+k] * prod q ----
    if (tid < ROWS) {
        f32x4 w;
        float p = s_q[tid];
        w.x = s_delta[tid];
        w.y = s_delta[tid + 1] * p;  p *= s_q[tid + 1];
        w.z = s_delta[tid + 2] * p;  p *= s_q[tid + 2];
        w.w = s_delta[tid + 3] * p;
        s_w[tid] = w;
    }
    __syncthreads();

    if (col0 + 256 + 3 >= T) return;  // full-tile fast path (T % 2048 == 0)

    // ---- per-thread column state: ratio, values for 2 chunks ----
    f32x4 r4[CHUNKS];
    f32x4 vv[CHUNKS];
    #pragma unroll
    for (int c = 0; c < CHUNKS; ++c) {
        int cc = col0 + c * 256;
        f32x4 ll = *(const f32x4*)(learner_lp + cc);
        f32x4 wl = *(const f32x4*)(worker_lp + cc);
        vv[c] = *(const f32x4*)(values + cc);
        f32x4 r;
        r.x = fminf(1.f, __expf(ll.x - wl.x));
        r.y = fminf(1.f, __expf(ll.y - wl.y));
        r.z = fminf(1.f, __expf(ll.z - wl.z));
        r.w = fminf(1.f, __expf(ll.w - wl.w));
        r4[c] = r;
    }

    size_t base = (size_t)t0 * (size_t)T + (size_t)col0;
    const int rmax = (t0 + ROWS <= T) ? ROWS : (T - t0);

    #pragma unroll 2
    for (int r = 0; r < rmax; ++r) {
        f32x4 w = s_w[r];                 // wave-uniform ds_read_b128 broadcast
        #pragma unroll
        for (int c = 0; c < CHUNKS; ++c) {
            f32x4 rr = r4[c];
            f32x4 g;
            g.x = fmaf(fmaf(fmaf(w.w, rr.x, w.z), rr.x, w.y), rr.x, w.x) - vv[c].x;
            g.y = fmaf(fmaf(fmaf(w.w, rr.y, w.z), rr.y, w.y), rr.y, w.x) - vv[c].y;
            g.z = fmaf(fmaf(fmaf(w.w, rr.z, w.z), rr.z, w.y), rr.z, w.x) - vv[c].z;
            g.w = fmaf(fmaf(fmaf(w.w, rr.w, w.z), rr.w, w.y), rr.w, w.x) - vv[c].w;
            __builtin_nontemporal_store(g, (f32x4*)(out + base + c * 256));
        }
        base += (size_t)T;
    }
}

extern "C" void kernel_launch(void* const* d_in, const int* in_sizes, int n_in,
                              void* d_out, int out_size, void* d_ws, size_t ws_size,
                              hipStream_t stream) {
    const float* rewards     = (const float*)d_in[0];
    const float* values      = (const float*)d_in[1];
    const float* next_values = (const float*)d_in[2];
    const float* dones       = (const float*)d_in[3];
    const float* worker_lp   = (const float*)d_in[4];
    const float* learner_lp  = (const float*)d_in[5];
    float* out = (float*)d_out;

    const int T = in_sizes[0];

    dim3 block(256);
    dim3 grid((T + 2048 - 1) / 2048, (T + 16 - 1) / 16);
    hipLaunchKernelGGL(vtrace_adv_kernel, grid, block, 0, stream,
                       rewards, values, next_values, dones,
                       worker_lp, learner_lp, out, T);
}

// Round 5
// 44.947 us; speedup vs baseline: 1.2044x; 1.2044x over previous
//
#include <hip/hip_runtime.h>

// V-trace advantage estimation, T x T output.
// out[t][j] = g_t(j) - values[j]
// g_t(j) = sum_{k>=0} delta_{t+k} * ratio_j^k * prod_{u=t}^{t+k-1} q_u
// with q_u = (1-gamma)*(1-done_u) <= 0.01, ratio_j <= 1.
// Truncate at K=4: dropped term <= |delta|*(0.01)^4 ~ 1e-7.
//
// Round 5: EXACT round-2 geometry (best: 47.6us, 2048 blocks = 8/CU,
// 1 f32x4 chunk/thread). Single variable changed: plain stores instead of
// nontemporal -> let the 256 MiB Infinity Cache (== output size) absorb
// the write stream instead of bypassing it.

typedef float f32x4 __attribute__((ext_vector_type(4)));

#define GAMMA_F 0.99f

__global__ __launch_bounds__(256) void vtrace_adv_kernel(
    const float* __restrict__ rewards,
    const float* __restrict__ values,
    const float* __restrict__ next_values,
    const float* __restrict__ dones,
    const float* __restrict__ worker_lp,
    const float* __restrict__ learner_lp,
    float* __restrict__ out,
    int T)
{
    constexpr int ROWS = 32;    // rows (t) per block  -> grid_y = T/32 = 256
    constexpr int K    = 4;     // Horner terms
    constexpr int EXT  = ROWS + K;

    __shared__ float s_delta[EXT];
    __shared__ float s_q[EXT];
    __shared__ f32x4 s_w[ROWS];   // per-row Horner coefficients, one b128 read

    const int tid = threadIdx.x;
    const int t0  = blockIdx.y * ROWS;
    const int c   = blockIdx.x * (256 * 4) + tid * 4;   // 4 columns per thread

    // ---- cooperative: delta[t], q[t] for window [t0, t0+EXT) ----
    if (tid < EXT) {
        int s = t0 + tid;
        float d = 0.f, q = 0.f;
        if (s < T) {
            float ratio = fminf(1.f, __expf(learner_lp[s] - worker_lp[s]));
            float nd = 1.f - dones[s];
            d = ratio * (rewards[s] + nd * GAMMA_F * next_values[s]);
            q = (1.f - GAMMA_F) * nd;
        }
        s_delta[tid] = d;
        s_q[tid] = q;
    }
    __syncthreads();

    // ---- per-row coefficients w[r][k] = delta[t+k] * prod_{u=t}^{t+k-1} q_u ----
    if (tid < ROWS) {
        f32x4 w;
        float p = s_q[tid];
        w.x = s_delta[tid];
        w.y = s_delta[tid + 1] * p;  p *= s_q[tid + 1];
        w.z = s_delta[tid + 2] * p;  p *= s_q[tid + 2];
        w.w = s_delta[tid + 3] * p;
        s_w[tid] = w;
    }
    __syncthreads();

    if (c + 3 >= T) return;  // no further barriers below

    // ---- per-thread column state: ratio_j, values_j (float4) ----
    f32x4 ll = *(const f32x4*)(learner_lp + c);
    f32x4 wl = *(const f32x4*)(worker_lp + c);
    f32x4 vv = *(const f32x4*)(values + c);
    f32x4 r4;
    r4.x = fminf(1.f, __expf(ll.x - wl.x));
    r4.y = fminf(1.f, __expf(ll.y - wl.y));
    r4.z = fminf(1.f, __expf(ll.z - wl.z));
    r4.w = fminf(1.f, __expf(ll.w - wl.w));

    size_t base = (size_t)t0 * (size_t)T + (size_t)c;
    const int rmax = (t0 + ROWS <= T) ? ROWS : (T - t0);

    #pragma unroll 4
    for (int r = 0; r < rmax; ++r) {
        f32x4 w = s_w[r];                 // wave-uniform ds_read_b128 broadcast
        // Horner: g = w0 + r*(w1 + r*(w2 + r*w3)); out = g - v
        float g0 = w.w, g1 = w.w, g2 = w.w, g3 = w.w;
        g0 = fmaf(g0, r4.x, w.z);
        g1 = fmaf(g1, r4.y, w.z);
        g2 = fmaf(g2, r4.z, w.z);
        g3 = fmaf(g3, r4.w, w.z);
        g0 = fmaf(g0, r4.x, w.y);
        g1 = fmaf(g1, r4.y, w.y);
        g2 = fmaf(g2, r4.z, w.y);
        g3 = fmaf(g3, r4.w, w.y);
        g0 = fmaf(g0, r4.x, w.x);
        g1 = fmaf(g1, r4.y, w.x);
        g2 = fmaf(g2, r4.z, w.x);
        g3 = fmaf(g3, r4.w, w.x);
        f32x4 o;
        o.x = g0 - vv.x;
        o.y = g1 - vv.y;
        o.z = g2 - vv.z;
        o.w = g3 - vv.w;
        *(f32x4*)(out + base) = o;        // plain store: L3 write-allocate
        base += (size_t)T;
    }
}

extern "C" void kernel_launch(void* const* d_in, const int* in_sizes, int n_in,
                              void* d_out, int out_size, void* d_ws, size_t ws_size,
                              hipStream_t stream) {
    const float* rewards     = (const float*)d_in[0];
    const float* values      = (const float*)d_in[1];
    const float* next_values = (const float*)d_in[2];
    const float* dones       = (const float*)d_in[3];
    const float* worker_lp   = (const float*)d_in[4];
    const float* learner_lp  = (const float*)d_in[5];
    float* out = (float*)d_out;

    const int T = in_sizes[0];

    dim3 block(256);
    dim3 grid((T + 1024 - 1) / 1024, (T + 32 - 1) / 32);
    hipLaunchKernelGGL(vtrace_adv_kernel, grid, block, 0, stream,
                       rewards, values, next_values, dones,
                       worker_lp, learner_lp, out, T);
}

// Round 6
// 44.704 us; speedup vs baseline: 1.2109x; 1.0054x over previous
//
#include <hip/hip_runtime.h>

// V-trace advantage estimation, T x T output.
// out[t][j] = g_t(j) - values[j]
// g_t(j) = sum_{k>=0} delta_{t+k} * ratio_j^k * prod_{u=t}^{t+k-1} q_u
// with q_u = (1-gamma)*(1-done_u) <= 0.01, ratio_j <= 1.
// Truncate at K=4: dropped term <= |delta|*(0.01)^4 ~ 1e-7.
//
// Round 6: round-5 kernel (plain stores, 44.9us = 5.97 TB/s), single
// variable changed: ROWS 32 -> 16, grid -> 4096 blocks = 2 scheduling
// rounds of 8 blocks/CU. Tests whether single-round scheduling (no tail
// backfill, ramp on critical path) is the residual vs fill's 7.1 TB/s.

typedef float f32x4 __attribute__((ext_vector_type(4)));

#define GAMMA_F 0.99f

__global__ __launch_bounds__(256) void vtrace_adv_kernel(
    const float* __restrict__ rewards,
    const float* __restrict__ values,
    const float* __restrict__ next_values,
    const float* __restrict__ dones,
    const float* __restrict__ worker_lp,
    const float* __restrict__ learner_lp,
    float* __restrict__ out,
    int T)
{
    constexpr int ROWS = 16;    // rows (t) per block  -> grid_y = T/16 = 512
    constexpr int K    = 4;     // Horner terms
    constexpr int EXT  = ROWS + K;

    __shared__ float s_delta[EXT];
    __shared__ float s_q[EXT];
    __shared__ f32x4 s_w[ROWS];   // per-row Horner coefficients, one b128 read

    const int tid = threadIdx.x;
    const int t0  = blockIdx.y * ROWS;
    const int c   = blockIdx.x * (256 * 4) + tid * 4;   // 4 columns per thread

    // ---- cooperative: delta[t], q[t] for window [t0, t0+EXT) ----
    if (tid < EXT) {
        int s = t0 + tid;
        float d = 0.f, q = 0.f;
        if (s < T) {
            float ratio = fminf(1.f, __expf(learner_lp[s] - worker_lp[s]));
            float nd = 1.f - dones[s];
            d = ratio * (rewards[s] + nd * GAMMA_F * next_values[s]);
            q = (1.f - GAMMA_F) * nd;
        }
        s_delta[tid] = d;
        s_q[tid] = q;
    }
    __syncthreads();

    // ---- per-row coefficients w[r][k] = delta[t+k] * prod_{u=t}^{t+k-1} q_u ----
    if (tid < ROWS) {
        f32x4 w;
        float p = s_q[tid];
        w.x = s_delta[tid];
        w.y = s_delta[tid + 1] * p;  p *= s_q[tid + 1];
        w.z = s_delta[tid + 2] * p;  p *= s_q[tid + 2];
        w.w = s_delta[tid + 3] * p;
        s_w[tid] = w;
    }
    __syncthreads();

    if (c + 3 >= T) return;  // no further barriers below

    // ---- per-thread column state: ratio_j, values_j (float4) ----
    f32x4 ll = *(const f32x4*)(learner_lp + c);
    f32x4 wl = *(const f32x4*)(worker_lp + c);
    f32x4 vv = *(const f32x4*)(values + c);
    f32x4 r4;
    r4.x = fminf(1.f, __expf(ll.x - wl.x));
    r4.y = fminf(1.f, __expf(ll.y - wl.y));
    r4.z = fminf(1.f, __expf(ll.z - wl.z));
    r4.w = fminf(1.f, __expf(ll.w - wl.w));

    size_t base = (size_t)t0 * (size_t)T + (size_t)c;
    const int rmax = (t0 + ROWS <= T) ? ROWS : (T - t0);

    #pragma unroll 4
    for (int r = 0; r < rmax; ++r) {
        f32x4 w = s_w[r];                 // wave-uniform ds_read_b128 broadcast
        // Horner: g = w0 + r*(w1 + r*(w2 + r*w3)); out = g - v
        float g0 = w.w, g1 = w.w, g2 = w.w, g3 = w.w;
        g0 = fmaf(g0, r4.x, w.z);
        g1 = fmaf(g1, r4.y, w.z);
        g2 = fmaf(g2, r4.z, w.z);
        g3 = fmaf(g3, r4.w, w.z);
        g0 = fmaf(g0, r4.x, w.y);
        g1 = fmaf(g1, r4.y, w.y);
        g2 = fmaf(g2, r4.z, w.y);
        g3 = fmaf(g3, r4.w, w.y);
        g0 = fmaf(g0, r4.x, w.x);
        g1 = fmaf(g1, r4.y, w.x);
        g2 = fmaf(g2, r4.z, w.x);
        g3 = fmaf(g3, r4.w, w.x);
        f32x4 o;
        o.x = g0 - vv.x;
        o.y = g1 - vv.y;
        o.z = g2 - vv.z;
        o.w = g3 - vv.w;
        *(f32x4*)(out + base) = o;        // plain store: L2/L3 write-allocate
        base += (size_t)T;
    }
}

extern "C" void kernel_launch(void* const* d_in, const int* in_sizes, int n_in,
                              void* d_out, int out_size, void* d_ws, size_t ws_size,
                              hipStream_t stream) {
    const float* rewards     = (const float*)d_in[0];
    const float* values      = (const float*)d_in[1];
    const float* next_values = (const float*)d_in[2];
    const float* dones       = (const float*)d_in[3];
    const float* worker_lp   = (const float*)d_in[4];
    const float* learner_lp  = (const float*)d_in[5];
    float* out = (float*)d_out;

    const int T = in_sizes[0];

    dim3 block(256);
    dim3 grid((T + 1024 - 1) / 1024, (T + 16 - 1) / 16);
    hipLaunchKernelGGL(vtrace_adv_kernel, grid, block, 0, stream,
                       rewards, values, next_values, dones,
                       worker_lp, learner_lp, out, T);
}